// Round 6
// baseline (1433.457 us; speedup 1.0000x reference)
//
#include <hip/hip_runtime.h>
#include <math.h>

// ---------------- problem constants ----------------
constexpr int Nn = 50000;
constexpr int Ee = 800000;
// output layout (f32 elements): [out_s N*64 | vec N*3 | node_feats_out N*256]
constexpr int VEC_OFF = Nn * 64;            // 3,200,000
constexpr int NF_OFF  = Nn * 67;            // 3,350,000

// counting-sort scratch lives in the out_s region (written by k_post LAST):
// cnt[NPAD] | offs[NPAD] | bsum[256] | perm[Ee]  = ~3.6 MB < 12.8 MB
constexpr int NBLK = 196;                   // scan blocks
constexpr int NPAD = NBLK * 256;            // 50176 >= Nn

// ---------------- ws layout (bytes) — total exactly 51.2 MB ----------------
constexpr size_t AS_OFF = 0;                // f32 N*64   12.8 MB (atomic accum)
constexpr size_t AV_OFF = 12800000;         // f32 N*192  38.4 MB (atomic accum)

__device__ __forceinline__ float silu(float x) { return x / (1.f + __expf(-x)); }

// ================= counting sort by rcv (CSR permutation) =================
__global__ __launch_bounds__(256) void k_hist(const int* __restrict__ rcv,
                                              unsigned* __restrict__ cnt) {
    int e = blockIdx.x * 256 + threadIdx.x;
    atomicAdd(&cnt[rcv[e]], 1u);
}

__global__ __launch_bounds__(256) void k_scan_local(const unsigned* __restrict__ cnt,
                                                    unsigned* __restrict__ offs,
                                                    unsigned* __restrict__ bsum) {
    __shared__ unsigned s[256];
    int t = threadIdx.x, i = blockIdx.x * 256 + t;
    unsigned v = cnt[i];
    s[t] = v; __syncthreads();
    for (int d = 1; d < 256; d <<= 1) {
        unsigned x = (t >= d) ? s[t - d] : 0u; __syncthreads();
        s[t] += x; __syncthreads();
    }
    offs[i] = s[t] - v;                       // exclusive within block
    if (t == 255) bsum[blockIdx.x] = s[255];  // block total
}

__global__ __launch_bounds__(256) void k_scan_bsum(unsigned* __restrict__ bsum) {
    __shared__ unsigned s[256];
    int t = threadIdx.x;
    unsigned v = (t < NBLK) ? bsum[t] : 0u;
    s[t] = v; __syncthreads();
    for (int d = 1; d < 256; d <<= 1) {
        unsigned x = (t >= d) ? s[t - d] : 0u; __syncthreads();
        s[t] += x; __syncthreads();
    }
    if (t < NBLK) bsum[t] = s[t] - v;         // exclusive block offsets
}

__global__ __launch_bounds__(256) void k_scan_add(unsigned* __restrict__ offs,
                                                  const unsigned* __restrict__ bsum) {
    int i = blockIdx.x * 256 + threadIdx.x;
    offs[i] += bsum[blockIdx.x];
}

__global__ __launch_bounds__(256) void k_scatter(const int* __restrict__ rcv,
                                                 unsigned* __restrict__ cursor,
                                                 unsigned* __restrict__ perm) {
    int e = blockIdx.x * 256 + threadIdx.x;
    unsigned p = atomicAdd(&cursor[rcv[e]], 1u);
    perm[p] = (unsigned)e;
}

// ================= K0: per-node up-projection =================
// up[n] stored INTERLEAVED as float4 per channel: up4[n*64 + k] =
// (s_up[k], vup0[k], vup1[k], vup2[k]) so k_edge gathers ONE dwordx4
// per edge per lane. Scratch target: node_feats_out region of out.
__global__ __launch_bounds__(256) void k_up(
    const float* __restrict__ nfeat,
    const float* __restrict__ Wsu, const float* __restrict__ Wvu,
    float4* __restrict__ up4) {
    __shared__ float sR[4][8][256];       // raw node rows per wave

    const int tid = threadIdx.x, lane = tid & 63, w = tid >> 6;
    const int nb = blockIdx.x * 32 + w * 8;

#pragma unroll
    for (int nn = 0; nn < 8; nn++) {
        int n = nb + nn;
        float4 nv = make_float4(0.f, 0.f, 0.f, 0.f);
        if (n < Nn) nv = *(const float4*)(nfeat + (size_t)n * 256 + lane * 4);
        *(float4*)(&sR[w][nn][lane * 4]) = nv;
    }
    // same-wave LDS write->read: in-order, no barrier needed

    float su[8], v0[8], v1[8], v2[8];
#pragma unroll
    for (int nn = 0; nn < 8; nn++) { su[nn]=0.f; v0[nn]=0.f; v1[nn]=0.f; v2[nn]=0.f; }

#pragma unroll 2
    for (int c = 0; c < 64; c++) {
        float u = Wsu[c * 64 + lane];      // lane = output channel
        float q = Wvu[c * 64 + lane];
#pragma unroll
        for (int nn = 0; nn < 8; nn++) {
            float sc = sR[w][nn][c];               // broadcast reads
            float a0 = sR[w][nn][64 + 3 * c + 0];  // v[c][i] raw layout
            float a1 = sR[w][nn][64 + 3 * c + 1];
            float a2 = sR[w][nn][64 + 3 * c + 2];
            su[nn] += sc * u;
            v0[nn] += a0 * q;
            v1[nn] += a1 * q;
            v2[nn] += a2 * q;
        }
    }
#pragma unroll
    for (int nn = 0; nn < 8; nn++) {
        int n = nb + nn;
        if (n < Nn)
            up4[(size_t)n * 64 + lane] = make_float4(su[nn], v0[nn], v1[nn], v2[nn]);
    }
}

// ================= K1: fused edge kernel, rcv-sorted order =================
// Round-4 structure (8 edges/wave, VGPR ~48, zero LDS conflicts) but edges
// consumed via perm (sorted by rcv). Consecutive edges share rcv (avg run
// 16) -> accumulate message in registers, flush ONE atomic set per run.
// Run detection via readfirstlane -> scalar branch, wave-uniform.
__global__ __launch_bounds__(256, 3) void k_edge(
    const float* __restrict__ vectors, const float* __restrict__ edge_feats,
    const int* __restrict__ snd_idx, const int* __restrict__ rcv_idx,
    const unsigned* __restrict__ perm,
    const float4* __restrict__ up4,
    const float* __restrict__ W1, const float* __restrict__ W2,
    float* __restrict__ a_s, float* __restrict__ a_v) {
    __shared__ float sEf[32 * 64];
    __shared__ float sH[32 * 64];
    __shared__ float sY[32 * 3];
    __shared__ int sSnd[32], sRcv[32];

    const int tid = threadIdx.x;
    const int e0 = blockIdx.x * 32;

    {   // stage 32 permuted ef rows (16 threads x 16B per row: 256B/row coalesced)
        for (int k = tid; k < 512; k += 256) {
            int row = k >> 4, c4 = k & 15;
            unsigned pe = perm[e0 + row];      // L1-hot (128B line / 32 edges)
            ((float4*)sEf)[k] = *(const float4*)(edge_feats + (size_t)pe * 64 + c4 * 4);
        }
    }
    if (tid < 32) {   // per-edge Y1 = sqrt(3)*rhat + indices (permuted)
        unsigned pe = perm[e0 + tid];
        float x = vectors[(size_t)pe * 3 + 0];
        float y = vectors[(size_t)pe * 3 + 1];
        float z = vectors[(size_t)pe * 3 + 2];
        float n = sqrtf(x * x + y * y + z * z) + 1e-12f;
        float s = 1.7320508075688772f / n;
        sY[tid * 3 + 0] = x * s; sY[tid * 3 + 1] = y * s; sY[tid * 3 + 2] = z * s;
        sSnd[tid] = snd_idx[pe];
        sRcv[tid] = rcv_idx[pe];
    }
    __syncthreads();

    const int lane = tid & 63, w = tid >> 6, m0 = w * 8;

    // ---- h = silu(ef @ W1) ----
    {
        float hacc[8];
#pragma unroll
        for (int e = 0; e < 8; e++) hacc[e] = 0.f;
        for (int c = 0; c < 64; c += 4) {
            float w0 = W1[(c + 0) * 64 + lane], w1 = W1[(c + 1) * 64 + lane],
                  w2 = W1[(c + 2) * 64 + lane], w3 = W1[(c + 3) * 64 + lane];
#pragma unroll
            for (int e = 0; e < 8; e++) {
                const float4 ef = *(const float4*)(&sEf[(m0 + e) * 64 + c]);
                hacc[e] += ef.x * w0 + ef.y * w1 + ef.z * w2 + ef.w * w3;
            }
        }
#pragma unroll
        for (int e = 0; e < 8; e++) sH[(m0 + e) * 64 + lane] = silu(hacc[e]);
        // sH rows are wave-private: same-wave write->read, no barrier needed
    }

    // ---- w = h @ W2 : wacc[q][e] = w[e][q*64 + lane] ----
    float wacc[5][8];
#pragma unroll
    for (int q = 0; q < 5; q++)
#pragma unroll
        for (int e = 0; e < 8; e++) wacc[q][e] = 0.f;
#pragma unroll 2
    for (int c = 0; c < 64; c++) {
        float wq0 = W2[c * 320 + 0 * 64 + lane];
        float wq1 = W2[c * 320 + 1 * 64 + lane];
        float wq2 = W2[c * 320 + 2 * 64 + lane];
        float wq3 = W2[c * 320 + 3 * 64 + lane];
        float wq4 = W2[c * 320 + 4 * 64 + lane];
#pragma unroll
        for (int e = 0; e < 8; e++) {
            float hb = sH[(m0 + e) * 64 + c];
            wacc[0][e] += hb * wq0; wacc[1][e] += hb * wq1; wacc[2][e] += hb * wq2;
            wacc[3][e] += hb * wq3; wacc[4][e] += hb * wq4;
        }
    }

    // ---- gather pre-projected rows: one dwordx4 per edge, all issued ----
    float4 g[8];
#pragma unroll
    for (int e = 0; e < 8; e++)
        g[e] = up4[(size_t)sSnd[m0 + e] * 64 + lane];

    // ---- message compute + run-combined scatter ----
    int curR = __builtin_amdgcn_readfirstlane(sRcv[m0]);
    float accS = 0.f, accV0 = 0.f, accV1 = 0.f, accV2 = 0.f;
#pragma unroll
    for (int e = 0; e < 8; e++) {
        const int rcv = __builtin_amdgcn_readfirstlane(sRcv[m0 + e]);
        const float Y0 = sY[(m0 + e) * 3 + 0];
        const float Y1 = sY[(m0 + e) * 3 + 1];
        const float Y2 = sY[(m0 + e) * 3 + 2];
        const float sj = g[e].x, vj0 = g[e].y, vj1 = g[e].z, vj2 = g[e].w;
        const float w0 = wacc[0][e], w1 = wacc[1][e], w2 = wacc[2][e],
                    w3 = wacc[3][e], w4 = wacc[4][e];
        float vdY = vj0 * Y0 + vj1 * Y1 + vj2 * Y2;
        float ms = w0 * sj + w1 * vdY;
        float cx = vj1 * Y2 - vj2 * Y1;
        float cy = vj2 * Y0 - vj0 * Y2;
        float cz = vj0 * Y1 - vj1 * Y0;
        float t = w2 * sj;
        float mv0 = t * Y0 + w3 * vj0 + w4 * cx;
        float mv1 = t * Y1 + w3 * vj1 + w4 * cy;
        float mv2 = t * Y2 + w3 * vj2 + w4 * cz;
        if (rcv != curR) {     // scalar (SGPR) compare -> uniform branch
            atomicAdd(a_s + (size_t)curR * 64 + lane, accS);
            float* avp = a_v + (size_t)curR * 192;
            atomicAdd(avp + lane,       accV0);
            atomicAdd(avp + 64 + lane,  accV1);
            atomicAdd(avp + 128 + lane, accV2);
            curR = rcv;
            accS = ms; accV0 = mv0; accV1 = mv1; accV2 = mv2;
        } else {
            accS += ms; accV0 += mv0; accV1 += mv1; accV2 += mv2;
        }
    }
    atomicAdd(a_s + (size_t)curR * 64 + lane, accS);
    {
        float* avp = a_v + (size_t)curR * 192;
        atomicAdd(avp + lane,       accV0);
        atomicAdd(avp + 64 + lane,  accV1);
        atomicAdd(avp + 128 + lane, accV2);
    }
}

// ================= K2: node post (round-4 version, unchanged) =================
__global__ __launch_bounds__(256) void k_post(
    const float* __restrict__ a_s, const float* __restrict__ a_v,
    const float* __restrict__ Wsp, const float* __restrict__ Wvp,
    const float* __restrict__ Ps1, const float* __restrict__ Ps2,
    const float* __restrict__ Ps3, const float* __restrict__ Pvv,
    const float* __restrict__ Pv1, const float* __restrict__ Pv2,
    const float* __restrict__ Pv3,
    const float* __restrict__ Rw1, const float* __restrict__ Rw2,
    const float* __restrict__ Rgate, const float* __restrict__ Rvmix,
    float* __restrict__ out) {
    __shared__ float Xb[4][8 * 256];   // a/16 -> (as2|av2) -> hr in s-section
    __shared__ float Yb[4][8 * 256];   // ps|pv0|pv1|pv2

    const int tid = threadIdx.x, lane = tid & 63, w = tid >> 6;
    const int nb = blockIdx.x * 32 + w * 8;   // first node of this wave
    float* X = &Xb[w][0];
    float* Y = &Yb[w][0];

    // ---- stage a_s/a_v (x 1/16) ----
#pragma unroll
    for (int nn = 0; nn < 8; nn++) {
        int n = nb + nn;
        if (n < Nn) {
            X[nn * 256 + lane]       = a_s[(size_t)n * 64 + lane] * 0.0625f;
            X[nn * 256 + 64 + lane]  = a_v[(size_t)n * 192 + lane] * 0.0625f;
            X[nn * 256 + 128 + lane] = a_v[(size_t)n * 192 + 64 + lane] * 0.0625f;
            X[nn * 256 + 192 + lane] = a_v[(size_t)n * 192 + 128 + lane] * 0.0625f;
        } else {
            X[nn * 256 + lane] = 0.f; X[nn * 256 + 64 + lane] = 0.f;
            X[nn * 256 + 128 + lane] = 0.f; X[nn * 256 + 192 + lane] = 0.f;
        }
    }

    // ---- phase A: as2 = a_s@Wsp ; av2_i = a_v_i@Wvp (lane = out channel) ----
    {
        float as2[8], ava[8], avb[8], avc[8];
#pragma unroll
        for (int nn = 0; nn < 8; nn++) { as2[nn]=0.f; ava[nn]=0.f; avb[nn]=0.f; avc[nn]=0.f; }
        for (int c = 0; c < 64; c++) {
            float wsp = Wsp[c * 64 + lane];
            float wvp = Wvp[c * 64 + lane];
#pragma unroll
            for (int nn = 0; nn < 8; nn++) {
                as2[nn] += X[nn * 256 + c] * wsp;
                ava[nn] += X[nn * 256 + 64 + c] * wvp;
                avb[nn] += X[nn * 256 + 128 + c] * wvp;
                avc[nn] += X[nn * 256 + 192 + c] * wvp;
            }
        }
#pragma unroll
        for (int nn = 0; nn < 8; nn++) {   // in-place (all reads done)
            X[nn * 256 + lane] = as2[nn];
            X[nn * 256 + 64 + lane] = ava[nn];
            X[nn * 256 + 128 + lane] = avb[nn];
            X[nn * 256 + 192 + lane] = avc[nn];
        }
    }

    // ---- phase B: ps, pv ----
    {
        float ps[8], pv0[8], pv1[8], pv2[8];
#pragma unroll
        for (int nn = 0; nn < 8; nn++) { ps[nn]=0.f; pv0[nn]=0.f; pv1[nn]=0.f; pv2[nn]=0.f; }
        for (int c = 0; c < 64; c++) {
            float p1 = Ps1[c * 64 + lane], p2 = Ps2[c * 64 + lane],
                  p3 = Ps3[c * 64 + lane], pv = Pvv[c * 64 + lane];
            float q1 = Pv1[c * 64 + lane], q2 = Pv2[c * 64 + lane],
                  q3 = Pv3[c * 64 + lane];
#pragma unroll
            for (int nn = 0; nn < 8; nn++) {
                float a  = X[nn * 256 + c];
                float b0 = X[nn * 256 + 64 + c];
                float b1 = X[nn * 256 + 128 + c];
                float b2 = X[nn * 256 + 192 + c];
                float a2 = a * a, a3 = a2 * a;
                float vv = b0 * b0 + b1 * b1 + b2 * b2;
                ps[nn] += a * p1 + a2 * p2 + a3 * p3 + vv * pv;
                float qq = q1 + a * q2 + a2 * q3;
                pv0[nn] += b0 * qq; pv1[nn] += b1 * qq; pv2[nn] += b2 * qq;
            }
        }
#pragma unroll
        for (int nn = 0; nn < 8; nn++) {
            Y[nn * 256 + lane] = ps[nn];
            Y[nn * 256 + 64 + lane] = pv0[nn];
            Y[nn * 256 + 128 + lane] = pv1[nn];
            Y[nn * 256 + 192 + lane] = pv2[nn];
            int n = nb + nn;
            if (n < Nn) {   // node_feats_out = [ps | pv (k*3+i)]
                float* nf = out + NF_OFF + (size_t)n * 256;
                nf[lane] = ps[nn];
                nf[64 + lane * 3 + 0] = pv0[nn];
                nf[64 + lane * 3 + 1] = pv1[nn];
                nf[64 + lane * 3 + 2] = pv2[nn];
            }
        }
    }

    // ---- phase C: hr = silu(ps @ Rw1) -> X s-section (dead) ----
    {
        float hr[8];
#pragma unroll
        for (int nn = 0; nn < 8; nn++) hr[nn] = 0.f;
        for (int c = 0; c < 64; c++) {
            float r1 = Rw1[c * 64 + lane];
#pragma unroll
            for (int nn = 0; nn < 8; nn++) hr[nn] += Y[nn * 256 + c] * r1;
        }
#pragma unroll
        for (int nn = 0; nn < 8; nn++) X[nn * 256 + lane] = silu(hr[nn]);
    }

    // ---- gate = silu(hr @ Rgate) : per-node wave reduction ----
    float gate[8];
    {
        float rg = Rgate[lane];
#pragma unroll
        for (int nn = 0; nn < 8; nn++) {
            float p = X[nn * 256 + lane] * rg;
            p += __shfl_xor(p, 1);  p += __shfl_xor(p, 2);
            p += __shfl_xor(p, 4);  p += __shfl_xor(p, 8);
            p += __shfl_xor(p, 16); p += __shfl_xor(p, 32);
            gate[nn] = silu(p);
        }
    }

    // ---- out_s = hr @ Rw2 ----
    {
        float os[8];
#pragma unroll
        for (int nn = 0; nn < 8; nn++) os[nn] = 0.f;
        for (int c = 0; c < 64; c++) {
            float r2 = Rw2[c * 64 + lane];
#pragma unroll
            for (int nn = 0; nn < 8; nn++) os[nn] += X[nn * 256 + c] * r2;
        }
#pragma unroll
        for (int nn = 0; nn < 8; nn++) {
            int n = nb + nn;
            if (n < Nn) out[(size_t)n * 64 + lane] = os[nn];
        }
    }

    // ---- vec = (sum_k pv_i[k]*Rvmix[k]) * gate ----
    {
        float vm = Rvmix[lane];
#pragma unroll
        for (int nn = 0; nn < 8; nn++) {
            int n = nb + nn;
#pragma unroll
            for (int j = 0; j < 3; j++) {
                float p = Y[nn * 256 + 64 + j * 64 + lane] * vm;
                p += __shfl_xor(p, 1);  p += __shfl_xor(p, 2);
                p += __shfl_xor(p, 4);  p += __shfl_xor(p, 8);
                p += __shfl_xor(p, 16); p += __shfl_xor(p, 32);
                if (lane == j && n < Nn)
                    out[VEC_OFF + (size_t)n * 3 + j] = p * gate[nn];
            }
        }
    }
}

// ---------------- host ----------------
extern "C" void kernel_launch(void* const* d_in, const int* in_sizes, int n_in,
                              void* d_out, int out_size, void* d_ws, size_t ws_size,
                              hipStream_t stream) {
    (void)in_sizes; (void)n_in; (void)out_size; (void)ws_size;
    const float* vectors    = (const float*)d_in[0];
    const float* node_feats = (const float*)d_in[2];
    const float* edge_feats = (const float*)d_in[3];
    const int*   edge_index = (const int*)d_in[4];
    const float* W_s_up   = (const float*)d_in[5];
    const float* W_v_up   = (const float*)d_in[6];
    const float* mlp_w1   = (const float*)d_in[7];
    const float* mlp_w2   = (const float*)d_in[8];
    const float* W_s_post = (const float*)d_in[9];
    const float* W_v_post = (const float*)d_in[10];
    const float* P_s1 = (const float*)d_in[11];
    const float* P_s2 = (const float*)d_in[12];
    const float* P_s3 = (const float*)d_in[13];
    const float* P_vv = (const float*)d_in[14];
    const float* P_v1 = (const float*)d_in[15];
    const float* P_v2 = (const float*)d_in[16];
    const float* P_v3 = (const float*)d_in[17];
    const float* R_w1 = (const float*)d_in[18];
    const float* R_w2 = (const float*)d_in[19];
    const float* R_gate = (const float*)d_in[20];
    const float* R_vmix = (const float*)d_in[21];

    char* ws = (char*)d_ws;
    float* a_s = (float*)(ws + AS_OFF);
    float* a_v = (float*)(ws + AV_OFF);
    float* outp = (float*)d_out;
    // scratch in out_s region (overwritten by k_post at the very end):
    unsigned* cnt  = (unsigned*)outp;           // NPAD
    unsigned* offs = cnt + NPAD;                // NPAD (becomes scatter cursor)
    unsigned* bsum = offs + NPAD;               // 256
    unsigned* perm = bsum + 256;                // Ee   (total ~3.6 MB < 12.8 MB)
    // up-projection scratch: node_feats_out region (51.2 MB), float4/channel.
    float4* up4 = (float4*)(outp + NF_OFF);

    const int* snd = edge_index;
    const int* rcv = edge_index + Ee;

    // zero segment-sum accumulators (51.2 MB) + histogram
    hipMemsetAsync(ws, 0, 51200000, stream);
    hipMemsetAsync(cnt, 0, NPAD * sizeof(unsigned), stream);

    // counting sort by rcv -> perm
    k_hist      <<<Ee / 256, 256, 0, stream>>>(rcv, cnt);
    k_scan_local<<<NBLK,     256, 0, stream>>>(cnt, offs, bsum);
    k_scan_bsum <<<1,        256, 0, stream>>>(bsum);
    k_scan_add  <<<NBLK,     256, 0, stream>>>(offs, bsum);
    k_scatter   <<<Ee / 256, 256, 0, stream>>>(rcv, offs, perm);

    k_up<<<(Nn + 31) / 32, 256, 0, stream>>>(node_feats, W_s_up, W_v_up, up4);

    k_edge<<<Ee / 32, 256, 0, stream>>>(vectors, edge_feats, snd, rcv,
                                        perm, up4, mlp_w1, mlp_w2, a_s, a_v);

    k_post<<<(Nn + 31) / 32, 256, 0, stream>>>(a_s, a_v,
                                               W_s_post, W_v_post,
                                               P_s1, P_s2, P_s3, P_vv,
                                               P_v1, P_v2, P_v3,
                                               R_w1, R_w2, R_gate, R_vmix,
                                               outp);
}

// Round 7
// 1111.088 us; speedup vs baseline: 1.2901x; 1.2901x over previous
//
#include <hip/hip_runtime.h>
#include <math.h>

// ---------------- problem constants ----------------
constexpr int Nn = 50000;
constexpr int Ee = 800000;
// output layout (f32 elements): [out_s N*64 | vec N*3 | node_feats_out N*256]
constexpr int VEC_OFF = Nn * 64;            // 3,200,000
constexpr int NF_OFF  = Nn * 67;            // 3,350,000

// out_s region scratch (overwritten by k_post at the very end):
// cnt[NPAD] | offs[NPAD] | bsum[256] | perm[Ee]  (~3.6 MB), then at +4MB:
// wsw: swizzled bf16 hi/lo weight fragments (96 KB)
constexpr int NBLK = 196;                   // scan blocks
constexpr int NPAD = NBLK * 256;            // 50176 >= Nn
constexpr int WSW_F32_OFF = 1000000;        // 4 MB into out_s region

// ---------------- ws layout (bytes) — total exactly 51.2 MB ----------------
constexpr size_t AS_OFF = 0;                // f32 N*64   12.8 MB (atomic accum)
constexpr size_t AV_OFF = 12800000;         // f32 N*192  38.4 MB (atomic accum)

typedef short  bf16x8 __attribute__((ext_vector_type(8)));
typedef float  f32x4  __attribute__((ext_vector_type(4)));

#define MFMA16(a, b, c) __builtin_amdgcn_mfma_f32_16x16x32_bf16(a, b, c, 0, 0, 0)

__device__ __forceinline__ float silu(float x) { return x / (1.f + __expf(-x)); }

// bf16 truncation split: x ~= hi + lo, |err| ~ 2^-16 |x|
__device__ __forceinline__ unsigned short bfhi_u(float x) {
    union { float f; unsigned u; } c; c.f = x; return (unsigned short)(c.u >> 16);
}
__device__ __forceinline__ float bftrunc_f(float x) {
    union { float f; unsigned u; } c; c.f = x; c.u &= 0xffff0000u; return c.f;
}
// split 8 contiguous f32 (LDS) into hi/lo bf16 fragments
__device__ __forceinline__ void split8(const float* p, bf16x8& hi, bf16x8& lo) {
#pragma unroll
    for (int j = 0; j < 8; j++) {
        float x = p[j];
        hi[j] = (short)bfhi_u(x);
        lo[j] = (short)bfhi_u(x - bftrunc_f(x));
    }
}

// ================= counting sort by rcv (CSR permutation) =================
__global__ __launch_bounds__(256) void k_hist(const int* __restrict__ rcv,
                                              unsigned* __restrict__ cnt) {
    int e = blockIdx.x * 256 + threadIdx.x;
    atomicAdd(&cnt[rcv[e]], 1u);
}

__global__ __launch_bounds__(256) void k_scan_local(const unsigned* __restrict__ cnt,
                                                    unsigned* __restrict__ offs,
                                                    unsigned* __restrict__ bsum) {
    __shared__ unsigned s[256];
    int t = threadIdx.x, i = blockIdx.x * 256 + t;
    unsigned v = cnt[i];
    s[t] = v; __syncthreads();
    for (int d = 1; d < 256; d <<= 1) {
        unsigned x = (t >= d) ? s[t - d] : 0u; __syncthreads();
        s[t] += x; __syncthreads();
    }
    offs[i] = s[t] - v;
    if (t == 255) bsum[blockIdx.x] = s[255];
}

__global__ __launch_bounds__(256) void k_scan_bsum(unsigned* __restrict__ bsum) {
    __shared__ unsigned s[256];
    int t = threadIdx.x;
    unsigned v = (t < NBLK) ? bsum[t] : 0u;
    s[t] = v; __syncthreads();
    for (int d = 1; d < 256; d <<= 1) {
        unsigned x = (t >= d) ? s[t - d] : 0u; __syncthreads();
        s[t] += x; __syncthreads();
    }
    if (t < NBLK) bsum[t] = s[t] - v;
}

__global__ __launch_bounds__(256) void k_scan_add(unsigned* __restrict__ offs,
                                                  const unsigned* __restrict__ bsum) {
    int i = blockIdx.x * 256 + threadIdx.x;
    offs[i] += bsum[blockIdx.x];
}

__global__ __launch_bounds__(256) void k_scatter(const int* __restrict__ rcv,
                                                 unsigned* __restrict__ cursor,
                                                 unsigned* __restrict__ perm) {
    int e = blockIdx.x * 256 + threadIdx.x;
    unsigned p = atomicAdd(&cursor[rcv[e]], 1u);
    perm[p] = (unsigned)e;
}

// ================= weight prep: bf16 hi/lo fragments, fragment order ======
// frag element j of (lane) holds W[k][n], k = ks*32 + (lane>>4)*8 + j,
// n = nt*16 + (lane&15). Same mapping is used on the A-side (split8 reads
// k-contiguous), so any HW k-slot permutation cancels (A/B symmetric).
// W1: frags [(q2*4+nt)*2+ks]  (q2: 0=hi,1=lo; nt<4)
// W2: frags [(q2*20+nt)*2+ks] at +8192 shorts
__global__ __launch_bounds__(256) void k_wprep(const float* __restrict__ W1,
                                               const float* __restrict__ W2,
                                               unsigned short* __restrict__ wsw) {
    int t = blockIdx.x * 256 + threadIdx.x;   // 0..6143
    int lane = t & 63;
    int ks = (t >> 6) & 1;
    int idx = t >> 7;                          // 0..47
    int nt_all = idx % 24;
    int q2 = idx / 24;                         // 0 hi, 1 lo
    int g = lane >> 4, l15 = lane & 15;

    unsigned short* dst;
    float vals[8];
    if (nt_all < 4) {
        int n = nt_all * 16 + l15;
#pragma unroll
        for (int j = 0; j < 8; j++) {
            int k = ks * 32 + g * 8 + j;
            vals[j] = W1[k * 64 + n];
        }
        dst = wsw + (size_t)(((q2 * 4 + nt_all) * 2 + ks) * 64 + lane) * 8;
    } else {
        int nt = nt_all - 4;
        int n = nt * 16 + l15;
#pragma unroll
        for (int j = 0; j < 8; j++) {
            int k = ks * 32 + g * 8 + j;
            vals[j] = W2[k * 320 + n];
        }
        dst = wsw + 8192 + (size_t)(((q2 * 20 + nt) * 2 + ks) * 64 + lane) * 8;
    }
    bf16x8 o;
#pragma unroll
    for (int j = 0; j < 8; j++) {
        float x = vals[j];
        o[j] = q2 ? (short)bfhi_u(x - bftrunc_f(x)) : (short)bfhi_u(x);
    }
    *(bf16x8*)dst = o;
}

// ================= K0: per-node up-projection (unchanged) =================
__global__ __launch_bounds__(256) void k_up(
    const float* __restrict__ nfeat,
    const float* __restrict__ Wsu, const float* __restrict__ Wvu,
    float4* __restrict__ up4) {
    __shared__ float sR[4][8][256];

    const int tid = threadIdx.x, lane = tid & 63, w = tid >> 6;
    const int nb = blockIdx.x * 32 + w * 8;

#pragma unroll
    for (int nn = 0; nn < 8; nn++) {
        int n = nb + nn;
        float4 nv = make_float4(0.f, 0.f, 0.f, 0.f);
        if (n < Nn) nv = *(const float4*)(nfeat + (size_t)n * 256 + lane * 4);
        *(float4*)(&sR[w][nn][lane * 4]) = nv;
    }

    float su[8], v0[8], v1[8], v2[8];
#pragma unroll
    for (int nn = 0; nn < 8; nn++) { su[nn]=0.f; v0[nn]=0.f; v1[nn]=0.f; v2[nn]=0.f; }

#pragma unroll 2
    for (int c = 0; c < 64; c++) {
        float u = Wsu[c * 64 + lane];
        float q = Wvu[c * 64 + lane];
#pragma unroll
        for (int nn = 0; nn < 8; nn++) {
            float sc = sR[w][nn][c];
            float a0 = sR[w][nn][64 + 3 * c + 0];
            float a1 = sR[w][nn][64 + 3 * c + 1];
            float a2 = sR[w][nn][64 + 3 * c + 2];
            su[nn] += sc * u;
            v0[nn] += a0 * q;
            v1[nn] += a1 * q;
            v2[nn] += a2 * q;
        }
    }
#pragma unroll
    for (int nn = 0; nn < 8; nn++) {
        int n = nb + nn;
        if (n < Nn)
            up4[(size_t)n * 64 + lane] = make_float4(su[nn], v0[nn], v1[nn], v2[nn]);
    }
}

// ================= K1: MFMA edge kernel, rcv-sorted order =================
// Block = 64 edges, 4 waves. G1: H = silu(EF@W1) (wave w -> H cols w*16..).
// G2 per M-tile (16 edges): each wave 5 N-tiles of W = H@W2, dump to LDS,
// message phase (4 edges/wave) with run-combined atomics.
// bf16 hi/lo split everywhere: (ah+al)(bh+bl) ~ ah*bh + ah*bl + al*bh.
__global__ __launch_bounds__(256, 3) void k_edge(
    const float* __restrict__ vectors, const float* __restrict__ edge_feats,
    const int* __restrict__ snd_idx, const int* __restrict__ rcv_idx,
    const unsigned* __restrict__ perm,
    const float4* __restrict__ up4,
    const unsigned short* __restrict__ wsw,
    float* __restrict__ a_s, float* __restrict__ a_v) {
    __shared__ float sU[5184];        // union: EF f32 [64][68] | Wmsg f32 [16][324]
    __shared__ float sH[64 * 68];
    __shared__ float sY[64 * 3];
    __shared__ int sSnd[64], sRcv[64];

    const int tid = threadIdx.x;
    const int e0 = blockIdx.x * 64;
    const int lane = tid & 63, w = tid >> 6, g = lane >> 4, l15 = lane & 15;

    if (tid < 64) {   // per-edge Y1 + indices (permuted)
        unsigned pe = perm[e0 + tid];
        float x = vectors[(size_t)pe * 3 + 0];
        float y = vectors[(size_t)pe * 3 + 1];
        float z = vectors[(size_t)pe * 3 + 2];
        float n = sqrtf(x * x + y * y + z * z) + 1e-12f;
        float s = 1.7320508075688772f / n;
        sY[tid * 3 + 0] = x * s; sY[tid * 3 + 1] = y * s; sY[tid * 3 + 2] = z * s;
        sSnd[tid] = snd_idx[pe];
        sRcv[tid] = rcv_idx[pe];
    }
    // stage EF f32 [64][68-padded]: 64 rows x 16 chunks of 16B
    for (int kk = tid; kk < 1024; kk += 256) {
        int row = kk >> 4, part = kk & 15;
        unsigned pe = perm[e0 + row];
        *(f32x4*)(&sU[row * 68 + part * 4]) =
            *(const f32x4*)(edge_feats + (size_t)pe * 64 + part * 4);
    }
    __syncthreads();

    const bf16x8* W1f = (const bf16x8*)wsw;
    const bf16x8* W2f = (const bf16x8*)(wsw + 8192);

    // ---- G1: H = silu(EF @ W1); wave w computes H cols [w*16, w*16+16) ----
    {
        const f32x4 z4 = {0.f, 0.f, 0.f, 0.f};
        f32x4 acc1[4] = {z4, z4, z4, z4};
        bf16x8 b1h[2], b1l[2];
#pragma unroll
        for (int ks = 0; ks < 2; ks++) {
            b1h[ks] = W1f[((0 * 4 + w) * 2 + ks) * 64 + lane];
            b1l[ks] = W1f[((1 * 4 + w) * 2 + ks) * 64 + lane];
        }
#pragma unroll
        for (int mt = 0; mt < 4; mt++) {
#pragma unroll
            for (int ks = 0; ks < 2; ks++) {
                bf16x8 ah, al;
                split8(&sU[(mt * 16 + l15) * 68 + ks * 32 + 8 * g], ah, al);
                acc1[mt] = MFMA16(ah, b1h[ks], acc1[mt]);
                acc1[mt] = MFMA16(ah, b1l[ks], acc1[mt]);
                acc1[mt] = MFMA16(al, b1h[ks], acc1[mt]);
            }
        }
        // C layout (m89-verified): row = g*4 + i (edge in tile), col = l15
#pragma unroll
        for (int mt = 0; mt < 4; mt++)
#pragma unroll
            for (int i = 0; i < 4; i++)
                sH[(mt * 16 + g * 4 + i) * 68 + w * 16 + l15] = silu(acc1[mt][i]);
    }
    __syncthreads();   // sH complete; sU(EF) dead from here

    // ---- G2 + message, per M-tile of 16 edges ----
    for (int mt = 0; mt < 4; mt++) {
        bf16x8 a2h[2], a2l[2];
#pragma unroll
        for (int ks = 0; ks < 2; ks++)
            split8(&sH[(mt * 16 + l15) * 68 + ks * 32 + 8 * g], a2h[ks], a2l[ks]);

#pragma unroll
        for (int q = 0; q < 5; q++) {
            int nt = w * 5 + q;        // wave w owns W cols [w*80, w*80+80)
            f32x4 acc = {0.f, 0.f, 0.f, 0.f};
#pragma unroll
            for (int ks = 0; ks < 2; ks++) {
                bf16x8 bh = W2f[((0 * 20 + nt) * 2 + ks) * 64 + lane];
                bf16x8 bl = W2f[((1 * 20 + nt) * 2 + ks) * 64 + lane];
                acc = MFMA16(a2h[ks], bh, acc);
                acc = MFMA16(a2h[ks], bl, acc);
                acc = MFMA16(a2l[ks], bh, acc);
            }
#pragma unroll
            for (int i = 0; i < 4; i++)
                sU[(g * 4 + i) * 324 + nt * 16 + l15] = acc[i];
        }
        __syncthreads();   // all 320 cols of this tile's W in sU

        // message: wave w handles 4 sorted edges of this tile
        float4 gg[4];
#pragma unroll
        for (int t = 0; t < 4; t++)
            gg[t] = up4[(size_t)sSnd[mt * 16 + w * 4 + t] * 64 + lane];

        int curR = __builtin_amdgcn_readfirstlane(sRcv[mt * 16 + w * 4]);
        float accS = 0.f, aV0 = 0.f, aV1 = 0.f, aV2 = 0.f;
#pragma unroll
        for (int t = 0; t < 4; t++) {
            const int le = w * 4 + t, eb = mt * 16 + le;
            const int rcv = __builtin_amdgcn_readfirstlane(sRcv[eb]);
            const float w0 = sU[le * 324 + 0 * 64 + lane];
            const float w1 = sU[le * 324 + 1 * 64 + lane];
            const float w2 = sU[le * 324 + 2 * 64 + lane];
            const float w3 = sU[le * 324 + 3 * 64 + lane];
            const float w4 = sU[le * 324 + 4 * 64 + lane];
            const float Y0 = sY[eb * 3 + 0];
            const float Y1 = sY[eb * 3 + 1];
            const float Y2 = sY[eb * 3 + 2];
            const float sj = gg[t].x, vj0 = gg[t].y, vj1 = gg[t].z, vj2 = gg[t].w;
            float vdY = vj0 * Y0 + vj1 * Y1 + vj2 * Y2;
            float ms = w0 * sj + w1 * vdY;
            float cx = vj1 * Y2 - vj2 * Y1;
            float cy = vj2 * Y0 - vj0 * Y2;
            float cz = vj0 * Y1 - vj1 * Y0;
            float tt = w2 * sj;
            float mv0 = tt * Y0 + w3 * vj0 + w4 * cx;
            float mv1 = tt * Y1 + w3 * vj1 + w4 * cy;
            float mv2 = tt * Y2 + w3 * vj2 + w4 * cz;
            if (rcv != curR) {   // SGPR compare -> uniform branch
                atomicAdd(a_s + (size_t)curR * 64 + lane, accS);
                float* avp = a_v + (size_t)curR * 192;
                atomicAdd(avp + lane,       aV0);
                atomicAdd(avp + 64 + lane,  aV1);
                atomicAdd(avp + 128 + lane, aV2);
                curR = rcv;
                accS = ms; aV0 = mv0; aV1 = mv1; aV2 = mv2;
            } else {
                accS += ms; aV0 += mv0; aV1 += mv1; aV2 += mv2;
            }
        }
        atomicAdd(a_s + (size_t)curR * 64 + lane, accS);
        {
            float* avp = a_v + (size_t)curR * 192;
            atomicAdd(avp + lane,       aV0);
            atomicAdd(avp + 64 + lane,  aV1);
            atomicAdd(avp + 128 + lane, aV2);
        }
        __syncthreads();   // sU reused next tile
    }
}

// ================= K2: node post (unchanged, known-good) =================
__global__ __launch_bounds__(256) void k_post(
    const float* __restrict__ a_s, const float* __restrict__ a_v,
    const float* __restrict__ Wsp, const float* __restrict__ Wvp,
    const float* __restrict__ Ps1, const float* __restrict__ Ps2,
    const float* __restrict__ Ps3, const float* __restrict__ Pvv,
    const float* __restrict__ Pv1, const float* __restrict__ Pv2,
    const float* __restrict__ Pv3,
    const float* __restrict__ Rw1, const float* __restrict__ Rw2,
    const float* __restrict__ Rgate, const float* __restrict__ Rvmix,
    float* __restrict__ out) {
    __shared__ float Xb[4][8 * 256];
    __shared__ float Yb[4][8 * 256];

    const int tid = threadIdx.x, lane = tid & 63, w = tid >> 6;
    const int nb = blockIdx.x * 32 + w * 8;
    float* X = &Xb[w][0];
    float* Y = &Yb[w][0];

#pragma unroll
    for (int nn = 0; nn < 8; nn++) {
        int n = nb + nn;
        if (n < Nn) {
            X[nn * 256 + lane]       = a_s[(size_t)n * 64 + lane] * 0.0625f;
            X[nn * 256 + 64 + lane]  = a_v[(size_t)n * 192 + lane] * 0.0625f;
            X[nn * 256 + 128 + lane] = a_v[(size_t)n * 192 + 64 + lane] * 0.0625f;
            X[nn * 256 + 192 + lane] = a_v[(size_t)n * 192 + 128 + lane] * 0.0625f;
        } else {
            X[nn * 256 + lane] = 0.f; X[nn * 256 + 64 + lane] = 0.f;
            X[nn * 256 + 128 + lane] = 0.f; X[nn * 256 + 192 + lane] = 0.f;
        }
    }

    {
        float as2[8], ava[8], avb[8], avc[8];
#pragma unroll
        for (int nn = 0; nn < 8; nn++) { as2[nn]=0.f; ava[nn]=0.f; avb[nn]=0.f; avc[nn]=0.f; }
        for (int c = 0; c < 64; c++) {
            float wsp = Wsp[c * 64 + lane];
            float wvp = Wvp[c * 64 + lane];
#pragma unroll
            for (int nn = 0; nn < 8; nn++) {
                as2[nn] += X[nn * 256 + c] * wsp;
                ava[nn] += X[nn * 256 + 64 + c] * wvp;
                avb[nn] += X[nn * 256 + 128 + c] * wvp;
                avc[nn] += X[nn * 256 + 192 + c] * wvp;
            }
        }
#pragma unroll
        for (int nn = 0; nn < 8; nn++) {
            X[nn * 256 + lane] = as2[nn];
            X[nn * 256 + 64 + lane] = ava[nn];
            X[nn * 256 + 128 + lane] = avb[nn];
            X[nn * 256 + 192 + lane] = avc[nn];
        }
    }

    {
        float ps[8], pv0[8], pv1[8], pv2[8];
#pragma unroll
        for (int nn = 0; nn < 8; nn++) { ps[nn]=0.f; pv0[nn]=0.f; pv1[nn]=0.f; pv2[nn]=0.f; }
        for (int c = 0; c < 64; c++) {
            float p1 = Ps1[c * 64 + lane], p2 = Ps2[c * 64 + lane],
                  p3 = Ps3[c * 64 + lane], pv = Pvv[c * 64 + lane];
            float q1 = Pv1[c * 64 + lane], q2 = Pv2[c * 64 + lane],
                  q3 = Pv3[c * 64 + lane];
#pragma unroll
            for (int nn = 0; nn < 8; nn++) {
                float a  = X[nn * 256 + c];
                float b0 = X[nn * 256 + 64 + c];
                float b1 = X[nn * 256 + 128 + c];
                float b2 = X[nn * 256 + 192 + c];
                float a2 = a * a, a3 = a2 * a;
                float vv = b0 * b0 + b1 * b1 + b2 * b2;
                ps[nn] += a * p1 + a2 * p2 + a3 * p3 + vv * pv;
                float qq = q1 + a * q2 + a2 * q3;
                pv0[nn] += b0 * qq; pv1[nn] += b1 * qq; pv2[nn] += b2 * qq;
            }
        }
#pragma unroll
        for (int nn = 0; nn < 8; nn++) {
            Y[nn * 256 + lane] = ps[nn];
            Y[nn * 256 + 64 + lane] = pv0[nn];
            Y[nn * 256 + 128 + lane] = pv1[nn];
            Y[nn * 256 + 192 + lane] = pv2[nn];
            int n = nb + nn;
            if (n < Nn) {
                float* nf = out + NF_OFF + (size_t)n * 256;
                nf[lane] = ps[nn];
                nf[64 + lane * 3 + 0] = pv0[nn];
                nf[64 + lane * 3 + 1] = pv1[nn];
                nf[64 + lane * 3 + 2] = pv2[nn];
            }
        }
    }

    {
        float hr[8];
#pragma unroll
        for (int nn = 0; nn < 8; nn++) hr[nn] = 0.f;
        for (int c = 0; c < 64; c++) {
            float r1 = Rw1[c * 64 + lane];
#pragma unroll
            for (int nn = 0; nn < 8; nn++) hr[nn] += Y[nn * 256 + c] * r1;
        }
#pragma unroll
        for (int nn = 0; nn < 8; nn++) X[nn * 256 + lane] = silu(hr[nn]);
    }

    float gate[8];
    {
        float rg = Rgate[lane];
#pragma unroll
        for (int nn = 0; nn < 8; nn++) {
            float p = X[nn * 256 + lane] * rg;
            p += __shfl_xor(p, 1);  p += __shfl_xor(p, 2);
            p += __shfl_xor(p, 4);  p += __shfl_xor(p, 8);
            p += __shfl_xor(p, 16); p += __shfl_xor(p, 32);
            gate[nn] = silu(p);
        }
    }

    {
        float os[8];
#pragma unroll
        for (int nn = 0; nn < 8; nn++) os[nn] = 0.f;
        for (int c = 0; c < 64; c++) {
            float r2 = Rw2[c * 64 + lane];
#pragma unroll
            for (int nn = 0; nn < 8; nn++) os[nn] += X[nn * 256 + c] * r2;
        }
#pragma unroll
        for (int nn = 0; nn < 8; nn++) {
            int n = nb + nn;
            if (n < Nn) out[(size_t)n * 64 + lane] = os[nn];
        }
    }

    {
        float vm = Rvmix[lane];
#pragma unroll
        for (int nn = 0; nn < 8; nn++) {
            int n = nb + nn;
#pragma unroll
            for (int j = 0; j < 3; j++) {
                float p = Y[nn * 256 + 64 + j * 64 + lane] * vm;
                p += __shfl_xor(p, 1);  p += __shfl_xor(p, 2);
                p += __shfl_xor(p, 4);  p += __shfl_xor(p, 8);
                p += __shfl_xor(p, 16); p += __shfl_xor(p, 32);
                if (lane == j && n < Nn)
                    out[VEC_OFF + (size_t)n * 3 + j] = p * gate[nn];
            }
        }
    }
}

// ---------------- host ----------------
extern "C" void kernel_launch(void* const* d_in, const int* in_sizes, int n_in,
                              void* d_out, int out_size, void* d_ws, size_t ws_size,
                              hipStream_t stream) {
    (void)in_sizes; (void)n_in; (void)out_size; (void)ws_size;
    const float* vectors    = (const float*)d_in[0];
    const float* node_feats = (const float*)d_in[2];
    const float* edge_feats = (const float*)d_in[3];
    const int*   edge_index = (const int*)d_in[4];
    const float* W_s_up   = (const float*)d_in[5];
    const float* W_v_up   = (const float*)d_in[6];
    const float* mlp_w1   = (const float*)d_in[7];
    const float* mlp_w2   = (const float*)d_in[8];
    const float* W_s_post = (const float*)d_in[9];
    const float* W_v_post = (const float*)d_in[10];
    const float* P_s1 = (const float*)d_in[11];
    const float* P_s2 = (const float*)d_in[12];
    const float* P_s3 = (const float*)d_in[13];
    const float* P_vv = (const float*)d_in[14];
    const float* P_v1 = (const float*)d_in[15];
    const float* P_v2 = (const float*)d_in[16];
    const float* P_v3 = (const float*)d_in[17];
    const float* R_w1 = (const float*)d_in[18];
    const float* R_w2 = (const float*)d_in[19];
    const float* R_gate = (const float*)d_in[20];
    const float* R_vmix = (const float*)d_in[21];

    char* ws = (char*)d_ws;
    float* a_s = (float*)(ws + AS_OFF);
    float* a_v = (float*)(ws + AV_OFF);
    float* outp = (float*)d_out;
    // out_s region scratch (k_post writes out_s last):
    unsigned* cnt  = (unsigned*)outp;                       // NPAD
    unsigned* offs = cnt + NPAD;                            // NPAD (cursor)
    unsigned* bsum = offs + NPAD;                           // 256
    unsigned* perm = bsum + 256;                            // Ee (ends ~3.6MB)
    unsigned short* wsw = (unsigned short*)(outp + WSW_F32_OFF);  // 96 KB @4MB
    // up-projection scratch: node_feats_out region (51.2 MB)
    float4* up4 = (float4*)(outp + NF_OFF);

    const int* snd = edge_index;
    const int* rcv = edge_index + Ee;

    hipMemsetAsync(ws, 0, 51200000, stream);
    hipMemsetAsync(cnt, 0, NPAD * sizeof(unsigned), stream);

    // counting sort by rcv -> perm
    k_hist      <<<Ee / 256, 256, 0, stream>>>(rcv, cnt);
    k_scan_local<<<NBLK,     256, 0, stream>>>(cnt, offs, bsum);
    k_scan_bsum <<<1,        256, 0, stream>>>(bsum);
    k_scan_add  <<<NBLK,     256, 0, stream>>>(offs, bsum);
    k_scatter   <<<Ee / 256, 256, 0, stream>>>(rcv, offs, perm);

    k_wprep<<<24, 256, 0, stream>>>(mlp_w1, mlp_w2, wsw);
    k_up<<<(Nn + 31) / 32, 256, 0, stream>>>(node_feats, W_s_up, W_v_up, up4);

    k_edge<<<Ee / 64, 256, 0, stream>>>(vectors, edge_feats, snd, rcv,
                                        perm, up4, wsw, a_s, a_v);

    k_post<<<(Nn + 31) / 32, 256, 0, stream>>>(a_s, a_v,
                                               W_s_post, W_v_post,
                                               P_s1, P_s2, P_s3, P_vv,
                                               P_v1, P_v2, P_v3,
                                               R_w1, R_w2, R_gate, R_vmix,
                                               outp);
}

// Round 12
// 975.727 us; speedup vs baseline: 1.4691x; 1.1387x over previous
//
#include <hip/hip_runtime.h>
#include <math.h>

// ---------------- problem constants ----------------
constexpr int Nn = 50000;
constexpr int Ee = 800000;
// output layout (f32 elements): [out_s N*64 | vec N*3 | node_feats_out N*256]
constexpr int VEC_OFF = Nn * 64;            // 3,200,000
constexpr int NF_OFF  = Nn * 67;            // 3,350,000

// out_s region scratch (overwritten by k_post at the very end):
// cnt[NPAD] | offs[NPAD] | bsum[256] | perm[Ee]  (~3.6 MB), then at +4MB:
// wsw: swizzled bf16 hi/lo W1/W2 fragments (96 KB) — read ONLY by k_edge
// (k_post must NOT read out_s-region scratch: it writes out_s itself).
constexpr int NBLK = 196;                   // scan blocks
constexpr int NPAD = NBLK * 256;            // 50176 >= Nn
constexpr int WSW_F32_OFF = 1000000;        // 4 MB into out_s region

// ---------------- ws layout (bytes) — total exactly 51.2 MB ----------------
constexpr size_t AS_OFF = 0;                // f32 N*64   12.8 MB (atomic accum)
constexpr size_t AV_OFF = 12800000;         // f32 N*192  38.4 MB (atomic accum)

typedef short  bf16x8 __attribute__((ext_vector_type(8)));
typedef float  f32x4  __attribute__((ext_vector_type(4)));

#define MFMA16(a, b, c) __builtin_amdgcn_mfma_f32_16x16x32_bf16(a, b, c, 0, 0, 0)

__device__ __forceinline__ float silu(float x) { return x / (1.f + __expf(-x)); }

// RNE bf16 split: x = hi + lo + e, |e| ~ 2^-18 |x|
__device__ __forceinline__ void rne_split(float x, short& h, short& l) {
    union { float f; unsigned u; } c; c.f = x;
    unsigned r = c.u + 0x7fffu + ((c.u >> 16) & 1u);
    h = (short)(r >> 16);
    union { float f; unsigned u; } hf; hf.u = (r >> 16) << 16;
    union { float f; unsigned u; } d; d.f = x - hf.f;
    unsigned r2 = d.u + 0x7fffu + ((d.u >> 16) & 1u);
    l = (short)(r2 >> 16);
}
// split 8 f32 (regs/LDS) into hi/lo bf16 fragments
__device__ __forceinline__ void afrag(const float* v, bf16x8& hi, bf16x8& lo) {
#pragma unroll
    for (int j = 0; j < 8; j++) { short h, l; rne_split(v[j], h, l); hi[j] = h; lo[j] = l; }
}
// B-fragment directly from global f32 matrix (row-major K x LDN):
// elem j = W[ks*32+8g+j][nt*16+l15] — same k-map as the A side, so any HW
// k-slot permutation cancels (A/B symmetric).
__device__ __forceinline__ void bfrag(const float* __restrict__ W, int ldn,
                                      int nt, int ks, int g, int l15,
                                      bf16x8& bh, bf16x8& bl) {
    const float* p = W + (size_t)(ks * 32 + 8 * g) * ldn + nt * 16 + l15;
#pragma unroll
    for (int j = 0; j < 8; j++) { short h, l; rne_split(p[(size_t)j * ldn], h, l); bh[j] = h; bl[j] = l; }
}
// 3-term split product: (ah+al)(bh+bl) ~ ah*bh + ah*bl + al*bh
__device__ __forceinline__ f32x4 mm3(bf16x8 ah, bf16x8 al, bf16x8 bh, bf16x8 bl, f32x4 c) {
    c = MFMA16(ah, bh, c);
    c = MFMA16(ah, bl, c);
    c = MFMA16(al, bh, c);
    return c;
}

// ================= counting sort by rcv (CSR permutation) =================
__global__ __launch_bounds__(256) void k_hist(const int* __restrict__ rcv,
                                              unsigned* __restrict__ cnt) {
    int e = blockIdx.x * 256 + threadIdx.x;
    atomicAdd(&cnt[rcv[e]], 1u);
}

__global__ __launch_bounds__(256) void k_scan_local(const unsigned* __restrict__ cnt,
                                                    unsigned* __restrict__ offs,
                                                    unsigned* __restrict__ bsum) {
    __shared__ unsigned s[256];
    int t = threadIdx.x, i = blockIdx.x * 256 + t;
    unsigned v = cnt[i];
    s[t] = v; __syncthreads();
    for (int d = 1; d < 256; d <<= 1) {
        unsigned x = (t >= d) ? s[t - d] : 0u; __syncthreads();
        s[t] += x; __syncthreads();
    }
    offs[i] = s[t] - v;
    if (t == 255) bsum[blockIdx.x] = s[255];
}

__global__ __launch_bounds__(256) void k_scan_bsum(unsigned* __restrict__ bsum) {
    __shared__ unsigned s[256];
    int t = threadIdx.x;
    unsigned v = (t < NBLK) ? bsum[t] : 0u;
    s[t] = v; __syncthreads();
    for (int d = 1; d < 256; d <<= 1) {
        unsigned x = (t >= d) ? s[t - d] : 0u; __syncthreads();
        s[t] += x; __syncthreads();
    }
    if (t < NBLK) bsum[t] = s[t] - v;
}

__global__ __launch_bounds__(256) void k_scan_add(unsigned* __restrict__ offs,
                                                  const unsigned* __restrict__ bsum) {
    int i = blockIdx.x * 256 + threadIdx.x;
    offs[i] += bsum[blockIdx.x];
}

__global__ __launch_bounds__(256) void k_scatter(const int* __restrict__ rcv,
                                                 unsigned* __restrict__ cursor,
                                                 unsigned* __restrict__ perm) {
    int e = blockIdx.x * 256 + threadIdx.x;
    unsigned p = atomicAdd(&cursor[rcv[e]], 1u);
    perm[p] = (unsigned)e;
}

// ================= weight prep for k_edge (W1/W2, RNE split) =============
__global__ __launch_bounds__(256) void k_wprep(const float* __restrict__ W1,
                                               const float* __restrict__ W2,
                                               unsigned short* __restrict__ wsw) {
    int t = blockIdx.x * 256 + threadIdx.x;   // 0..6143
    int lane = t & 63;
    int ks = (t >> 6) & 1;
    int idx = t >> 7;                          // 0..47
    int nt_all = idx % 24;
    int q2 = idx / 24;                         // 0 hi, 1 lo
    int g = lane >> 4, l15 = lane & 15;

    unsigned short* dst;
    float vals[8];
    if (nt_all < 4) {
        int n = nt_all * 16 + l15;
#pragma unroll
        for (int j = 0; j < 8; j++) vals[j] = W1[(ks * 32 + g * 8 + j) * 64 + n];
        dst = wsw + (size_t)(((q2 * 4 + nt_all) * 2 + ks) * 64 + lane) * 8;
    } else {
        int nt = nt_all - 4;
        int n = nt * 16 + l15;
#pragma unroll
        for (int j = 0; j < 8; j++) vals[j] = W2[(ks * 32 + g * 8 + j) * 320 + n];
        dst = wsw + 8192 + (size_t)(((q2 * 20 + nt) * 2 + ks) * 64 + lane) * 8;
    }
    bf16x8 o;
#pragma unroll
    for (int j = 0; j < 8; j++) {
        short h, l; rne_split(vals[j], h, l);
        o[j] = q2 ? l : h;
    }
    *(bf16x8*)dst = o;
}

// ================= K0: per-node up-projection (unchanged) =================
__global__ __launch_bounds__(256) void k_up(
    const float* __restrict__ nfeat,
    const float* __restrict__ Wsu, const float* __restrict__ Wvu,
    float4* __restrict__ up4) {
    __shared__ float sR[4][8][256];

    const int tid = threadIdx.x, lane = tid & 63, w = tid >> 6;
    const int nb = blockIdx.x * 32 + w * 8;

#pragma unroll
    for (int nn = 0; nn < 8; nn++) {
        int n = nb + nn;
        float4 nv = make_float4(0.f, 0.f, 0.f, 0.f);
        if (n < Nn) nv = *(const float4*)(nfeat + (size_t)n * 256 + lane * 4);
        *(float4*)(&sR[w][nn][lane * 4]) = nv;
    }

    float su[8], v0[8], v1[8], v2[8];
#pragma unroll
    for (int nn = 0; nn < 8; nn++) { su[nn]=0.f; v0[nn]=0.f; v1[nn]=0.f; v2[nn]=0.f; }

#pragma unroll 2
    for (int c = 0; c < 64; c++) {
        float u = Wsu[c * 64 + lane];
        float q = Wvu[c * 64 + lane];
#pragma unroll
        for (int nn = 0; nn < 8; nn++) {
            float sc = sR[w][nn][c];
            float a0 = sR[w][nn][64 + 3 * c + 0];
            float a1 = sR[w][nn][64 + 3 * c + 1];
            float a2 = sR[w][nn][64 + 3 * c + 2];
            su[nn] += sc * u;
            v0[nn] += a0 * q;
            v1[nn] += a1 * q;
            v2[nn] += a2 * q;
        }
    }
#pragma unroll
    for (int nn = 0; nn < 8; nn++) {
        int n = nb + nn;
        if (n < Nn)
            up4[(size_t)n * 64 + lane] = make_float4(su[nn], v0[nn], v1[nn], v2[nn]);
    }
}

// ================= K1: MFMA edge kernel (round-7, RNE split) ==============
__global__ __launch_bounds__(256, 3) void k_edge(
    const float* __restrict__ vectors, const float* __restrict__ edge_feats,
    const int* __restrict__ snd_idx, const int* __restrict__ rcv_idx,
    const unsigned* __restrict__ perm,
    const float4* __restrict__ up4,
    const unsigned short* __restrict__ wsw,
    float* __restrict__ a_s, float* __restrict__ a_v) {
    __shared__ float sU[5184];        // union: EF f32 [64][68] | Wmsg f32 [16][324]
    __shared__ float sH[64 * 68];
    __shared__ float sY[64 * 3];
    __shared__ int sSnd[64], sRcv[64];

    const int tid = threadIdx.x;
    const int e0 = blockIdx.x * 64;
    const int lane = tid & 63, w = tid >> 6, g = lane >> 4, l15 = lane & 15;

    if (tid < 64) {
        unsigned pe = perm[e0 + tid];
        float x = vectors[(size_t)pe * 3 + 0];
        float y = vectors[(size_t)pe * 3 + 1];
        float z = vectors[(size_t)pe * 3 + 2];
        float n = sqrtf(x * x + y * y + z * z) + 1e-12f;
        float s = 1.7320508075688772f / n;
        sY[tid * 3 + 0] = x * s; sY[tid * 3 + 1] = y * s; sY[tid * 3 + 2] = z * s;
        sSnd[tid] = snd_idx[pe];
        sRcv[tid] = rcv_idx[pe];
    }
    for (int kk = tid; kk < 1024; kk += 256) {
        int row = kk >> 4, part = kk & 15;
        unsigned pe = perm[e0 + row];
        *(f32x4*)(&sU[row * 68 + part * 4]) =
            *(const f32x4*)(edge_feats + (size_t)pe * 64 + part * 4);
    }
    __syncthreads();

    const bf16x8* W1f = (const bf16x8*)wsw;
    const bf16x8* W2f = (const bf16x8*)(wsw + 8192);

    // ---- G1: H = silu(EF @ W1); wave w computes H cols [w*16, w*16+16) ----
    {
        const f32x4 z4 = {0.f, 0.f, 0.f, 0.f};
        f32x4 acc1[4] = {z4, z4, z4, z4};
        bf16x8 b1h[2], b1l[2];
#pragma unroll
        for (int ks = 0; ks < 2; ks++) {
            b1h[ks] = W1f[((0 * 4 + w) * 2 + ks) * 64 + lane];
            b1l[ks] = W1f[((1 * 4 + w) * 2 + ks) * 64 + lane];
        }
#pragma unroll
        for (int mt = 0; mt < 4; mt++) {
#pragma unroll
            for (int ks = 0; ks < 2; ks++) {
                bf16x8 ah, al;
                afrag(&sU[(mt * 16 + l15) * 68 + ks * 32 + 8 * g], ah, al);
                acc1[mt] = mm3(ah, al, b1h[ks], b1l[ks], acc1[mt]);
            }
        }
#pragma unroll
        for (int mt = 0; mt < 4; mt++)
#pragma unroll
            for (int i = 0; i < 4; i++)
                sH[(mt * 16 + g * 4 + i) * 68 + w * 16 + l15] = silu(acc1[mt][i]);
    }
    __syncthreads();

    // ---- G2 + message, per M-tile of 16 edges ----
    for (int mt = 0; mt < 4; mt++) {
        bf16x8 a2h[2], a2l[2];
#pragma unroll
        for (int ks = 0; ks < 2; ks++)
            afrag(&sH[(mt * 16 + l15) * 68 + ks * 32 + 8 * g], a2h[ks], a2l[ks]);

#pragma unroll
        for (int q = 0; q < 5; q++) {
            int nt = w * 5 + q;
            f32x4 acc = {0.f, 0.f, 0.f, 0.f};
#pragma unroll
            for (int ks = 0; ks < 2; ks++) {
                bf16x8 bh = W2f[((0 * 20 + nt) * 2 + ks) * 64 + lane];
                bf16x8 bl = W2f[((1 * 20 + nt) * 2 + ks) * 64 + lane];
                acc = mm3(a2h[ks], a2l[ks], bh, bl, acc);
            }
#pragma unroll
            for (int i = 0; i < 4; i++)
                sU[(g * 4 + i) * 324 + nt * 16 + l15] = acc[i];
        }
        __syncthreads();

        float4 gg[4];
#pragma unroll
        for (int t = 0; t < 4; t++)
            gg[t] = up4[(size_t)sSnd[mt * 16 + w * 4 + t] * 64 + lane];

        int curR = __builtin_amdgcn_readfirstlane(sRcv[mt * 16 + w * 4]);
        float accS = 0.f, aV0 = 0.f, aV1 = 0.f, aV2 = 0.f;
#pragma unroll
        for (int t = 0; t < 4; t++) {
            const int le = w * 4 + t, eb = mt * 16 + le;
            const int rcv = __builtin_amdgcn_readfirstlane(sRcv[eb]);
            const float w0 = sU[le * 324 + 0 * 64 + lane];
            const float w1 = sU[le * 324 + 1 * 64 + lane];
            const float w2 = sU[le * 324 + 2 * 64 + lane];
            const float w3 = sU[le * 324 + 3 * 64 + lane];
            const float w4 = sU[le * 324 + 4 * 64 + lane];
            const float Y0 = sY[eb * 3 + 0];
            const float Y1 = sY[eb * 3 + 1];
            const float Y2 = sY[eb * 3 + 2];
            const float sj = gg[t].x, vj0 = gg[t].y, vj1 = gg[t].z, vj2 = gg[t].w;
            float vdY = vj0 * Y0 + vj1 * Y1 + vj2 * Y2;
            float ms = w0 * sj + w1 * vdY;
            float cx = vj1 * Y2 - vj2 * Y1;
            float cy = vj2 * Y0 - vj0 * Y2;
            float cz = vj0 * Y1 - vj1 * Y0;
            float tt = w2 * sj;
            float mv0 = tt * Y0 + w3 * vj0 + w4 * cx;
            float mv1 = tt * Y1 + w3 * vj1 + w4 * cy;
            float mv2 = tt * Y2 + w3 * vj2 + w4 * cz;
            if (rcv != curR) {
                atomicAdd(a_s + (size_t)curR * 64 + lane, accS);
                float* avp = a_v + (size_t)curR * 192;
                atomicAdd(avp + lane,       aV0);
                atomicAdd(avp + 64 + lane,  aV1);
                atomicAdd(avp + 128 + lane, aV2);
                curR = rcv;
                accS = ms; aV0 = mv0; aV1 = mv1; aV2 = mv2;
            } else {
                accS += ms; aV0 += mv0; aV1 += mv1; aV2 += mv2;
            }
        }
        atomicAdd(a_s + (size_t)curR * 64 + lane, accS);
        {
            float* avp = a_v + (size_t)curR * 192;
            atomicAdd(avp + lane,       aV0);
            atomicAdd(avp + 64 + lane,  aV1);
            atomicAdd(avp + 128 + lane, aV2);
        }
        __syncthreads();
    }
}

// ================= K2: MFMA node post =================
// 4 waves x 16 nodes, ALL wave-private (no barriers). 4 LDS slots per wave
// [16 nodes][68ch]: in (a,b0,b1,b2) -> phase A out -> ps/hr transposes.
// All 15 contractions as 16x16x32 bf16 MFMA, hi/lo RNE split; B-frags
// built directly from global f32 weights (L1/L2-hot; can't use out_s
// scratch — this kernel writes out_s).
__global__ __launch_bounds__(256) void k_post(
    const float* __restrict__ a_s, const float* __restrict__ a_v,
    const float* __restrict__ Wsp, const float* __restrict__ Wvp,
    const float* __restrict__ Ps1, const float* __restrict__ Ps2,
    const float* __restrict__ Ps3, const float* __restrict__ Pvv,
    const float* __restrict__ Pv1, const float* __restrict__ Pv2,
    const float* __restrict__ Pv3,
    const float* __restrict__ Rw1, const float* __restrict__ Rw2,
    const float* __restrict__ Rgate, const float* __restrict__ Rvmix,
    float* __restrict__ out) {
    __shared__ float sQ[4][4][16 * 68];   // [wave][slot][node*68+ch]

    const int tid = threadIdx.x, lane = tid & 63, w = tid >> 6;
    const int g = lane >> 4, l15 = lane & 15;
    const int nb16 = blockIdx.x * 64 + w * 16;
    float* q0 = &sQ[w][0][0];
    float* q1 = &sQ[w][1][0];
    float* q2 = &sQ[w][2][0];
    float* q3 = &sQ[w][3][0];
    const f32x4 z4 = {0.f, 0.f, 0.f, 0.f};
    const int aoff0 = l15 * 68 + 8 * g;    // + ks*32 for k-slice

    // ---- stage a_s/a_v (/16) into slots (wave-private, no barrier) ----
#pragma unroll 4
    for (int nn = 0; nn < 16; nn++) {
        int n = nb16 + nn;
        float va = 0.f, vb = 0.f, vc = 0.f, vd = 0.f;
        if (n < Nn) {
            va = a_s[(size_t)n * 64 + lane] * 0.0625f;
            vb = a_v[(size_t)n * 192 + lane] * 0.0625f;
            vc = a_v[(size_t)n * 192 + 64 + lane] * 0.0625f;
            vd = a_v[(size_t)n * 192 + 128 + lane] * 0.0625f;
        }
        q0[nn * 68 + lane] = va; q1[nn * 68 + lane] = vb;
        q2[nn * 68 + lane] = vc; q3[nn * 68 + lane] = vd;
    }

    // ---- phase A: as2 = a@Wsp, av_i = b_i@Wvp ----
    {
        f32x4 aC[4] = {z4, z4, z4, z4}, b0C[4] = {z4, z4, z4, z4},
              b1C[4] = {z4, z4, z4, z4}, b2C[4] = {z4, z4, z4, z4};
#pragma unroll
        for (int ks = 0; ks < 2; ks++) {
            bf16x8 Ah[4], Al[4];
            afrag(&q0[aoff0 + ks * 32], Ah[0], Al[0]);
            afrag(&q1[aoff0 + ks * 32], Ah[1], Al[1]);
            afrag(&q2[aoff0 + ks * 32], Ah[2], Al[2]);
            afrag(&q3[aoff0 + ks * 32], Ah[3], Al[3]);
#pragma unroll
            for (int nt = 0; nt < 4; nt++) {
                bf16x8 bh, bl;
                bfrag(Wsp, 64, nt, ks, g, l15, bh, bl);
                aC[nt] = mm3(Ah[0], Al[0], bh, bl, aC[nt]);
                bfrag(Wvp, 64, nt, ks, g, l15, bh, bl);
                b0C[nt] = mm3(Ah[1], Al[1], bh, bl, b0C[nt]);
                b1C[nt] = mm3(Ah[2], Al[2], bh, bl, b1C[nt]);
                b2C[nt] = mm3(Ah[3], Al[3], bh, bl, b2C[nt]);
            }
        }
        // C-layout writeback (row = g*4+i, col = nt*16+l15); all reads done
#pragma unroll
        for (int nt = 0; nt < 4; nt++)
#pragma unroll
            for (int i = 0; i < 4; i++) {
                int r = (g * 4 + i) * 68 + nt * 16 + l15;
                q0[r] = aC[nt][i];  q1[r] = b0C[nt][i];
                q2[r] = b1C[nt][i]; q3[r] = b2C[nt][i];
            }
    }

    // ---- phase B ----
    float aFv[2][8];
#pragma unroll
    for (int ks = 0; ks < 2; ks++)
#pragma unroll
        for (int j = 0; j < 8; j++) aFv[ks][j] = q0[aoff0 + ks * 32 + j];

    f32x4 psC[4] = {z4, z4, z4, z4};
    f32x4 pv0C[4] = {z4, z4, z4, z4}, pv1C[4] = {z4, z4, z4, z4},
          pv2C[4] = {z4, z4, z4, z4};

    // ps = a@P1 + a2@P2 + a3@P3 + vv@Pvv
#pragma unroll
    for (int ks = 0; ks < 2; ks++) {
        float v2[8], v3[8], vv[8];
#pragma unroll
        for (int j = 0; j < 8; j++) {
            float a = aFv[ks][j];
            v2[j] = a * a; v3[j] = v2[j] * a;
            float b0 = q1[aoff0 + ks * 32 + j];
            float b1 = q2[aoff0 + ks * 32 + j];
            float b2 = q3[aoff0 + ks * 32 + j];
            vv[j] = b0 * b0 + b1 * b1 + b2 * b2;
        }
        bf16x8 A1h, A1l, A2h, A2l, A3h, A3l, AVh, AVl;
        afrag(aFv[ks], A1h, A1l); afrag(v2, A2h, A2l);
        afrag(v3, A3h, A3l);      afrag(vv, AVh, AVl);
#pragma unroll
        for (int nt = 0; nt < 4; nt++) {
            bf16x8 bh, bl;
            bfrag(Ps1, 64, nt, ks, g, l15, bh, bl); psC[nt] = mm3(A1h, A1l, bh, bl, psC[nt]);
            bfrag(Ps2, 64, nt, ks, g, l15, bh, bl); psC[nt] = mm3(A2h, A2l, bh, bl, psC[nt]);
            bfrag(Ps3, 64, nt, ks, g, l15, bh, bl); psC[nt] = mm3(A3h, A3l, bh, bl, psC[nt]);
            bfrag(Pvv, 64, nt, ks, g, l15, bh, bl); psC[nt] = mm3(AVh, AVl, bh, bl, psC[nt]);
        }
    }
    // ps: nf write + transpose to q0 (a dead; aFv held in regs)
#pragma unroll
    for (int nt = 0; nt < 4; nt++)
#pragma unroll
        for (int i = 0; i < 4; i++) {
            int r = g * 4 + i, n = nb16 + r;
            q0[r * 68 + nt * 16 + l15] = psC[nt][i];
            if (n < Nn)
                out[NF_OFF + (size_t)n * 256 + nt * 16 + l15] = psC[nt][i];
        }

    // pv_i = b_i@Pv1 + (a.b_i)@Pv2 + (a2.b_i)@Pv3
#pragma unroll
    for (int ks = 0; ks < 2; ks++) {
        bf16x8 Bh[9], Bl[9];   // [i*3 + {b, ab, a2b}]
#pragma unroll
        for (int i3 = 0; i3 < 3; i3++) {
            const float* qi = (i3 == 0) ? q1 : ((i3 == 1) ? q2 : q3);
            float bF[8], ab[8], a2b[8];
#pragma unroll
            for (int j = 0; j < 8; j++) {
                float b = qi[aoff0 + ks * 32 + j], a = aFv[ks][j];
                bF[j] = b; ab[j] = a * b; a2b[j] = a * a * b;
            }
            afrag(bF,  Bh[i3 * 3 + 0], Bl[i3 * 3 + 0]);
            afrag(ab,  Bh[i3 * 3 + 1], Bl[i3 * 3 + 1]);
            afrag(a2b, Bh[i3 * 3 + 2], Bl[i3 * 3 + 2]);
        }
#pragma unroll
        for (int nt = 0; nt < 4; nt++) {
            bf16x8 p1h, p1l, p2h, p2l, p3h, p3l;
            bfrag(Pv1, 64, nt, ks, g, l15, p1h, p1l);
            bfrag(Pv2, 64, nt, ks, g, l15, p2h, p2l);
            bfrag(Pv3, 64, nt, ks, g, l15, p3h, p3l);
            pv0C[nt] = mm3(Bh[0], Bl[0], p1h, p1l, pv0C[nt]);
            pv0C[nt] = mm3(Bh[1], Bl[1], p2h, p2l, pv0C[nt]);
            pv0C[nt] = mm3(Bh[2], Bl[2], p3h, p3l, pv0C[nt]);
            pv1C[nt] = mm3(Bh[3], Bl[3], p1h, p1l, pv1C[nt]);
            pv1C[nt] = mm3(Bh[4], Bl[4], p2h, p2l, pv1C[nt]);
            pv1C[nt] = mm3(Bh[5], Bl[5], p3h, p3l, pv1C[nt]);
            pv2C[nt] = mm3(Bh[6], Bl[6], p1h, p1l, pv2C[nt]);
            pv2C[nt] = mm3(Bh[7], Bl[7], p2h, p2l, pv2C[nt]);
            pv2C[nt] = mm3(Bh[8], Bl[8], p3h, p3l, pv2C[nt]);
        }
    }
    // nf pv writes
#pragma unroll
    for (int nt = 0; nt < 4; nt++)
#pragma unroll
        for (int i = 0; i < 4; i++) {
            int n = nb16 + g * 4 + i;
            if (n < Nn) {
                float* nf = out + NF_OFF + (size_t)n * 256 + 64;
                int c = nt * 16 + l15;
                nf[c * 3 + 0] = pv0C[nt][i];
                nf[c * 3 + 1] = pv1C[nt][i];
                nf[c * 3 + 2] = pv2C[nt][i];
            }
        }

    // ---- phase C: hr = silu(ps@Rw1); gate; os = hr@Rw2; vec ----
    f32x4 hrC[4] = {z4, z4, z4, z4};
#pragma unroll
    for (int ks = 0; ks < 2; ks++) {
        bf16x8 ah, al;
        afrag(&q0[aoff0 + ks * 32], ah, al);
#pragma unroll
        for (int nt = 0; nt < 4; nt++) {
            bf16x8 bh, bl;
            bfrag(Rw1, 64, nt, ks, g, l15, bh, bl);
            hrC[nt] = mm3(ah, al, bh, bl, hrC[nt]);
        }
    }
#pragma unroll
    for (int nt = 0; nt < 4; nt++)
#pragma unroll
        for (int i = 0; i < 4; i++) hrC[nt][i] = silu(hrC[nt][i]);

    float rg[4], gate4[4];
#pragma unroll
    for (int nt = 0; nt < 4; nt++) rg[nt] = Rgate[nt * 16 + l15];
#pragma unroll
    for (int ii = 0; ii < 4; ii++) {
        float p = hrC[0][ii] * rg[0] + hrC[1][ii] * rg[1] +
                  hrC[2][ii] * rg[2] + hrC[3][ii] * rg[3];
        p += __shfl_xor(p, 1); p += __shfl_xor(p, 2);
        p += __shfl_xor(p, 4); p += __shfl_xor(p, 8);
        gate4[ii] = silu(p);
    }
    // hr transpose -> q1 (b0 slot dead)
#pragma unroll
    for (int nt = 0; nt < 4; nt++)
#pragma unroll
        for (int i = 0; i < 4; i++)
            q1[(g * 4 + i) * 68 + nt * 16 + l15] = hrC[nt][i];

    f32x4 osC[4] = {z4, z4, z4, z4};
#pragma unroll
    for (int ks = 0; ks < 2; ks++) {
        bf16x8 ah, al;
        afrag(&q1[aoff0 + ks * 32], ah, al);
#pragma unroll
        for (int nt = 0; nt < 4; nt++) {
            bf16x8 bh, bl;
            bfrag(Rw2, 64, nt, ks, g, l15, bh, bl);
            osC[nt] = mm3(ah, al, bh, bl, osC[nt]);
        }
    }
#pragma unroll
    for (int nt = 0; nt < 4; nt++)
#pragma unroll
        for (int i = 0; i < 4; i++) {
            int n = nb16 + g * 4 + i;
            if (n < Nn) out[(size_t)n * 64 + nt * 16 + l15] = osC[nt][i];
        }

    float vm[4];
#pragma unroll
    for (int nt = 0; nt < 4; nt++) vm[nt] = Rvmix[nt * 16 + l15];
#pragma unroll
    for (int ii = 0; ii < 4; ii++) {
        int n = nb16 + g * 4 + ii;
        {
            float p = pv0C[0][ii] * vm[0] + pv0C[1][ii] * vm[1] +
                      pv0C[2][ii] * vm[2] + pv0C[3][ii] * vm[3];
            p += __shfl_xor(p, 1); p += __shfl_xor(p, 2);
            p += __shfl_xor(p, 4); p += __shfl_xor(p, 8);
            if (l15 == 0 && n < Nn) out[VEC_OFF + (size_t)n * 3 + 0] = p * gate4[ii];
        }
        {
            float p = pv1C[0][ii] * vm[0] + pv1C[1][ii] * vm[1] +
                      pv1C[2][ii] * vm[2] + pv1C[3][ii] * vm[3];
            p += __shfl_xor(p, 1); p += __shfl_xor(p, 2);
            p += __shfl_xor(p, 4); p += __shfl_xor(p, 8);
            if (l15 == 1 && n < Nn) out[VEC_OFF + (size_t)n * 3 + 1] = p * gate4[ii];
        }
        {
            float p = pv2C[0][ii] * vm[0] + pv2C[1][ii] * vm[1] +
                      pv2C[2][ii] * vm[2] + pv2C[3][ii] * vm[3];
            p += __shfl_xor(p, 1); p += __shfl_xor(p, 2);
            p += __shfl_xor(p, 4); p += __shfl_xor(p, 8);
            if (l15 == 2 && n < Nn) out[VEC_OFF + (size_t)n * 3 + 2] = p * gate4[ii];
        }
    }
}

// ---------------- host ----------------
extern "C" void kernel_launch(void* const* d_in, const int* in_sizes, int n_in,
                              void* d_out, int out_size, void* d_ws, size_t ws_size,
                              hipStream_t stream) {
    (void)in_sizes; (void)n_in; (void)out_size; (void)ws_size;
    const float* vectors    = (const float*)d_in[0];
    const float* node_feats = (const float*)d_in[2];
    const float* edge_feats = (const float*)d_in[3];
    const int*   edge_index = (const int*)d_in[4];
    const float* W_s_up   = (const float*)d_in[5];
    const float* W_v_up   = (const float*)d_in[6];
    const float* mlp_w1   = (const float*)d_in[7];
    const float* mlp_w2   = (const float*)d_in[8];
    const float* W_s_post = (const float*)d_in[9];
    const float* W_v_post = (const float*)d_in[10];
    const float* P_s1 = (const float*)d_in[11];
    const float* P_s2 = (const float*)d_in[12];
    const float* P_s3 = (const float*)d_in[13];
    const float* P_vv = (const float*)d_in[14];
    const float* P_v1 = (const float*)d_in[15];
    const float* P_v2 = (const float*)d_in[16];
    const float* P_v3 = (const float*)d_in[17];
    const float* R_w1 = (const float*)d_in[18];
    const float* R_w2 = (const float*)d_in[19];
    const float* R_gate = (const float*)d_in[20];
    const float* R_vmix = (const float*)d_in[21];

    char* ws = (char*)d_ws;
    float* a_s = (float*)(ws + AS_OFF);
    float* a_v = (float*)(ws + AV_OFF);
    float* outp = (float*)d_out;
    // out_s region scratch (k_post writes out_s last):
    unsigned* cnt  = (unsigned*)outp;                       // NPAD
    unsigned* offs = cnt + NPAD;                            // NPAD (cursor)
    unsigned* bsum = offs + NPAD;                           // 256
    unsigned* perm = bsum + 256;                            // Ee (ends ~3.6MB)
    unsigned short* wsw = (unsigned short*)(outp + WSW_F32_OFF);  // 96 KB @4MB
    // up-projection scratch: node_feats_out region (51.2 MB)
    float4* up4 = (float4*)(outp + NF_OFF);

    const int* snd = edge_index;
    const int* rcv = edge_index + Ee;

    hipMemsetAsync(ws, 0, 51200000, stream);
    hipMemsetAsync(cnt, 0, NPAD * sizeof(unsigned), stream);

    // counting sort by rcv -> perm
    k_hist      <<<Ee / 256, 256, 0, stream>>>(rcv, cnt);
    k_scan_local<<<NBLK,     256, 0, stream>>>(cnt, offs, bsum);
    k_scan_bsum <<<1,        256, 0, stream>>>(bsum);
    k_scan_add  <<<NBLK,     256, 0, stream>>>(offs, bsum);
    k_scatter   <<<Ee / 256, 256, 0, stream>>>(rcv, offs, perm);

    k_wprep<<<24, 256, 0, stream>>>(mlp_w1, mlp_w2, wsw);
    k_up<<<(Nn + 31) / 32, 256, 0, stream>>>(node_feats, W_s_up, W_v_up, up4);

    k_edge<<<Ee / 64, 256, 0, stream>>>(vectors, edge_feats, snd, rcv,
                                        perm, up4, wsw, a_s, a_v);

    k_post<<<(Nn + 63) / 64, 256, 0, stream>>>(a_s, a_v,
                                               W_s_post, W_v_post,
                                               P_s1, P_s2, P_s3, P_vv,
                                               P_v1, P_v2, P_v3,
                                               R_w1, R_w2, R_gate, R_vmix,
                                               outp);
}